// Round 11
// baseline (188.694 us; speedup 1.0000x reference)
//
#include <hip/hip_runtime.h>

typedef unsigned short u16;
typedef unsigned int u32;
typedef short bf16x8 __attribute__((ext_vector_type(8)));
typedef float f32x4 __attribute__((ext_vector_type(4)));
typedef u16 u16x4 __attribute__((ext_vector_type(4)));

#define NAG 32
#define STATE 512
#define EMBED 64
#define TB 64   // grid = 512 = 2 blocks/CU, one round

// d_ws bf16 layout (u16 element offsets), FRAGMENT-ORDER swizzled:
// FRAG_A [ks(16)][tt(16)][lane(64)][8] : WA B-frags, row=tt*16+(lane&15), col=ks*32+(lane>>4)*8+j
//        WA row space: 0-63 w1l1, 64-127 w2l1, 128-191 b1w, 192-255 b2l1
// FRAG_B [a(32)][h(2)][wv(4)][lane(64)][8] : w1l2 row=a*64+wv*16+(lane&15), col=h*32+(lane>>4)*8+j
// WC     [64][64] row-major passthrough
#define OFF_FRAGA 0
#define OFF_FRAGB 131072
#define OFF_W2L2  262144
#define WS_TOTAL  266240

__device__ __forceinline__ float bf2f(u16 u) {
    u32 i = ((u32)u) << 16; float f;
    __builtin_memcpy(&f, &i, 4); return f;
}
__device__ __forceinline__ u16 f2bf(float f) {
    u32 i; __builtin_memcpy(&i, &f, 4);
    return (u16)((i + 0x8000u) >> 16);
}
__device__ __forceinline__ bf16x8 ld8(const u16* p) {
    return *reinterpret_cast<const bf16x8*>(p);
}
__device__ __forceinline__ bf16x8 cvt8(f32x4 a, f32x4 b) {
    bf16x8 r;
#pragma unroll
    for (int i = 0; i < 4; ++i) r[i]     = (short)f2bf(a[i]);
#pragma unroll
    for (int i = 0; i < 4; ++i) r[i + 4] = (short)f2bf(b[i]);
    return r;
}

__global__ __launch_bounds__(256) void cvt_weights(
    const float* __restrict__ w1l1w, const float* __restrict__ w2l1w,
    const float* __restrict__ b1w,   const float* __restrict__ b2l1w,
    const float* __restrict__ w1l2w, const float* __restrict__ w2l2w,
    u16* __restrict__ ws)
{
    int idx = blockIdx.x * 256 + threadIdx.x;
    if (idx >= WS_TOTAL) return;
    float v;
    if (idx < OFF_FRAGB) {
        const int j = idx & 7, lane = (idx >> 3) & 63, tmp = idx >> 9;
        const int tt = tmp & 15, ks = tmp >> 4;
        const int m = lane & 15, quad = lane >> 4;
        const int row = tt * 16 + m, col = ks * 32 + quad * 8 + j;
        const int r = row & 63;
        const float* src = (row < 64) ? w1l1w : (row < 128) ? w2l1w
                          : (row < 192) ? b1w : b2l1w;
        v = src[r * STATE + col];
    } else if (idx < OFF_W2L2) {
        const int local = idx - OFF_FRAGB;
        const int j = local & 7, lane = (local >> 3) & 63, rest = local >> 9;
        const int wv = rest & 3, h = (rest >> 2) & 1, a = rest >> 3;
        const int m = lane & 15, quad = lane >> 4;
        const int row = a * 64 + wv * 16 + m, col = h * 32 + quad * 8 + j;
        v = w1l2w[row * EMBED + col];
    } else {
        v = w2l2w[idx - OFF_W2L2];
    }
    ws[idx] = f2bf(v);
}

__global__ __launch_bounds__(256, 2) void qmix_kernel(
    const float* __restrict__ qs,    const float* __restrict__ st,
    const u16*  __restrict__ wsb,
    const float* __restrict__ w1l1b, const float* __restrict__ w1l2b,
    const float* __restrict__ w2l1b, const float* __restrict__ w2l2b,
    const float* __restrict__ b1b,   const float* __restrict__ b2l1b,
    const float* __restrict__ b2l2w, const float* __restrict__ b2l2b,
    float* __restrict__ out)
{
    __shared__ u16  y[TB][264];       // 33 KB: [0:64) h1, [64:128) h2, [128:192) b1v, [192:256) hb
    __shared__ u16  hidb[TB][72];     // 9 KB hidden bf16
    __shared__ u16  qsT[NAG][72];     // 4.5 KB qs transposed [agent][sample] bf16
    __shared__ u16  w1bs[2048];       // 4 KB w1l2b bf16
    __shared__ float qacc[TB];
    __shared__ float b2wv[64];
    // total ~51 KB -> 2 blocks/CU

    const int t    = threadIdx.x;
    const int wave = t >> 6, lane = t & 63;
    const int m = lane & 15, quad = lane >> 4;
    const int sbase = blockIdx.x * TB;
    const int s0 = wave * 16;

    // ---- prologue: b2wv, w1bs, qsT ----
    if (t < 64) b2wv[t] = b2l2w[t];
    {
        f32x4 w0 = *reinterpret_cast<const f32x4*>(w1l2b + t * 8);
        f32x4 w1 = *reinterpret_cast<const f32x4*>(w1l2b + t * 8 + 4);
        *reinterpret_cast<bf16x8*>(&w1bs[t * 8]) = cvt8(w0, w1);
    }
    {
        const int a = t & 31, sg = (t >> 5) * 8;
#pragma unroll
        for (int k = 0; k < 8; ++k)
            qsT[a][sg + k] = f2bf(qs[(size_t)(sbase + sg + k) * NAG + a]);
    }

    // ---- Phase A: Y[64][256]; wave independent; fragment-direct, 2-stage pipeline ----
    const u16* pfA = wsb + lane * 8;                                   // + (ks*16+tt)*512
    const float* sp0 = st + (size_t)(sbase + s0 + m) * STATE + quad * 8;

    bf16x8 bb[2][16];
    f32x4 sa[2], sb[2];
#pragma unroll
    for (int tt = 0; tt < 16; ++tt) bb[0][tt] = ld8(pfA + tt * 512);
    sa[0] = *reinterpret_cast<const f32x4*>(sp0);
    sb[0] = *reinterpret_cast<const f32x4*>(sp0 + 4);

    f32x4 acc[16] = {};
#pragma unroll
    for (int ks = 0; ks < 16; ++ks) {
        const int cur = ks & 1, nxt = cur ^ 1;
        if (ks < 15) {
#pragma unroll
            for (int tt = 0; tt < 16; ++tt)
                bb[nxt][tt] = ld8(pfA + ((ks + 1) * 16 + tt) * 512);
            sa[nxt] = *reinterpret_cast<const f32x4*>(sp0 + (ks + 1) * 32);
            sb[nxt] = *reinterpret_cast<const f32x4*>(sp0 + (ks + 1) * 32 + 4);
        }
        bf16x8 af = cvt8(sa[cur], sb[cur]);
#pragma unroll
        for (int tt = 0; tt < 16; ++tt)
            acc[tt] = __builtin_amdgcn_mfma_f32_16x16x32_bf16(af, bb[cur][tt], acc[tt], 0, 0, 0);
    }
    // biases loaded after the K-loop (frees 16 VGPRs during the pipeline)
    float abias[16];
#pragma unroll
    for (int tt = 0; tt < 4; ++tt) abias[tt]      = w1l1b[tt * 16 + m];
#pragma unroll
    for (int tt = 0; tt < 4; ++tt) abias[tt + 4]  = w2l1b[tt * 16 + m];
#pragma unroll
    for (int tt = 0; tt < 4; ++tt) abias[tt + 8]  = b1b[tt * 16 + m];
#pragma unroll
    for (int tt = 0; tt < 4; ++tt) abias[tt + 12] = b2l1b[tt * 16 + m];
#pragma unroll
    for (int tt = 0; tt < 16; ++tt) {
        const bool isrelu = (tt < 8) || (tt >= 12);   // tiles 8..11 = b1v (linear)
        const int fcol = tt * 16 + m;
#pragma unroll
        for (int r = 0; r < 4; ++r) {
            float v = acc[tt][r] + abias[tt];
            if (isrelu) v = fmaxf(v, 0.f);
            y[s0 + quad * 4 + r][fcol] = f2bf(v);
        }
    }
    __syncthreads();

    // ---- Phase B: e-split; wave owns e=wave*16+m for all 64 samples; agent-pair pipeline ----
    const int e = wave * 16 + m;
    bf16x8 haf[4][2];
#pragma unroll
    for (int g = 0; g < 4; ++g) {
        haf[g][0] = *reinterpret_cast<const bf16x8*>(&y[g * 16 + m][quad * 8]);
        haf[g][1] = *reinterpret_cast<const bf16x8*>(&y[g * 16 + m][32 + quad * 8]);
    }

    const u16* pfB = wsb + OFF_FRAGB + (size_t)wave * 512 + lane * 8;  // + (a*2+h)*2048
    bf16x8 wb[2][2][2];   // [parity][aloc][h]
#pragma unroll
    for (int al = 0; al < 2; ++al)
#pragma unroll
        for (int h = 0; h < 2; ++h)
            wb[0][al][h] = ld8(pfB + (al * 2 + h) * 2048);

    f32x4 hacc[4] = {};
#pragma unroll
    for (int p = 0; p < 16; ++p) {
        const int cur = p & 1, nxt = cur ^ 1;
        if (p < 15) {
#pragma unroll
            for (int al = 0; al < 2; ++al)
#pragma unroll
                for (int h = 0; h < 2; ++h)
                    wb[nxt][al][h] = ld8(pfB + (((p + 1) * 2 + al) * 2 + h) * 2048);
        }
#pragma unroll
        for (int al = 0; al < 2; ++al) {
            const int a = p * 2 + al;
            const float bias = bf2f(w1bs[a * EMBED + e]);
#pragma unroll
            for (int g = 0; g < 4; ++g) {
                f32x4 pp = {};
                pp = __builtin_amdgcn_mfma_f32_16x16x32_bf16(haf[g][0], wb[cur][al][0], pp, 0, 0, 0);
                pp = __builtin_amdgcn_mfma_f32_16x16x32_bf16(haf[g][1], wb[cur][al][1], pp, 0, 0, 0);
                u16x4 qv = *reinterpret_cast<const u16x4*>(&qsT[a][g * 16 + quad * 4]);
#pragma unroll
                for (int r = 0; r < 4; ++r)
                    hacc[g][r] += bf2f((u16)qv[r]) * fabsf(pp[r] + bias);
            }
        }
    }
#pragma unroll
    for (int g = 0; g < 4; ++g)
#pragma unroll
        for (int r = 0; r < 4; ++r) {
            const int s = g * 16 + quad * 4 + r;
            float v = hacc[g][r] + bf2f(y[s][128 + e]);
            v = (v > 0.f) ? v : (__expf(v) - 1.f);
            hidb[s][e] = f2bf(v);
        }
    __syncthreads();

    // ---- Phase C: w2 = |h2 @ W2l2^T + b|; q = sum_e hidden*w2 (wave owns 16 samples) ----
    bf16x8 h2f0 = *reinterpret_cast<const bf16x8*>(&y[s0 + m][64 + quad * 8]);
    bf16x8 h2f1 = *reinterpret_cast<const bf16x8*>(&y[s0 + m][96 + quad * 8]);

    f32x4 qp = {};
#pragma unroll
    for (int tp = 0; tp < 4; ++tp) {
        const u16* wc = wsb + OFF_W2L2 + (size_t)(tp * 16 + m) * EMBED + quad * 8;
        bf16x8 b0 = ld8(wc);
        bf16x8 b1 = ld8(wc + 32);
        f32x4 p = {};
        p = __builtin_amdgcn_mfma_f32_16x16x32_bf16(h2f0, b0, p, 0, 0, 0);
        p = __builtin_amdgcn_mfma_f32_16x16x32_bf16(h2f1, b1, p, 0, 0, 0);
        const float bias = w2l2b[tp * 16 + m];
#pragma unroll
        for (int r = 0; r < 4; ++r)
            qp[r] += bf2f(hidb[s0 + quad * 4 + r][tp * 16 + m]) * fabsf(p[r] + bias);
    }
#pragma unroll
    for (int off = 1; off < 16; off <<= 1) {
#pragma unroll
        for (int r = 0; r < 4; ++r) qp[r] += __shfl_xor(qp[r], off, 64);
    }
    if (m == 0) {
#pragma unroll
        for (int r = 0; r < 4; ++r) qacc[s0 + quad * 4 + r] = qp[r];
    }
    __syncthreads();

    // ---- Phase D: b2 + final sum (LDS-only) ----
    if (t < TB) {
        float q = qacc[t] + b2l2b[0];
        float acc2 = 0.f;
#pragma unroll
        for (int kk = 0; kk < 8; ++kk) {
            bf16x8 hv = *reinterpret_cast<const bf16x8*>(&y[t][192 + kk * 8]);
#pragma unroll
            for (int j = 0; j < 8; ++j)
                acc2 += bf2f((u16)hv[j]) * b2wv[kk * 8 + j];
        }
        out[sbase + t] = q + acc2;
    }
}

extern "C" void kernel_launch(void* const* d_in, const int* in_sizes, int n_in,
                              void* d_out, int out_size, void* d_ws, size_t ws_size,
                              hipStream_t stream)
{
    const float* qs    = (const float*)d_in[0];
    const float* st    = (const float*)d_in[1];
    const float* w1l1w = (const float*)d_in[2];
    const float* w1l1b = (const float*)d_in[3];
    const float* w1l2w = (const float*)d_in[4];
    const float* w1l2b = (const float*)d_in[5];
    const float* w2l1w = (const float*)d_in[6];
    const float* w2l1b = (const float*)d_in[7];
    const float* w2l2w = (const float*)d_in[8];
    const float* w2l2b = (const float*)d_in[9];
    const float* b1w   = (const float*)d_in[10];
    const float* b1b   = (const float*)d_in[11];
    const float* b2l1w = (const float*)d_in[12];
    const float* b2l1b = (const float*)d_in[13];
    const float* b2l2w = (const float*)d_in[14];
    const float* b2l2b = (const float*)d_in[15];

    u16* wsb = (u16*)d_ws;

    cvt_weights<<<(WS_TOTAL + 255) / 256, 256, 0, stream>>>(
        w1l1w, w2l1w, b1w, b2l1w, w1l2w, w2l2w, wsb);

    int B = in_sizes[0] / NAG;        // 32768
    int grid = B / TB;                // 512 = 2 blocks/CU
    qmix_kernel<<<grid, 256, 0, stream>>>(
        qs, st, wsb,
        w1l1b, w1l2b, w2l1b, w2l2b, b1b, b2l1b, b2l2w, b2l2b,
        (float*)d_out);
}